// Round 5
// baseline (179.521 us; speedup 1.0000x reference)
//
#include <hip/hip_runtime.h>

typedef _Float16 f16;
typedef f16 f16x4 __attribute__((ext_vector_type(4)));
typedef f16 f16x8 __attribute__((ext_vector_type(8)));
typedef float f32x4 __attribute__((ext_vector_type(4)));

#define N_EMBD 768
#define HS 64
#define NB 4
#define SEQ 4096
#define NTOK (NB * SEQ)
#define KSTEPS (N_EMBD / 32)   // 24

// ws layout (bytes)
#define OFF_Q  (3 * KSTEPS * 4 * 64 * 16)        // packed weights: 294912
#define OFF_K  (OFF_Q + NTOK * HS * 2)
#define OFF_VT (OFF_K + NTOK * HS * 2)
#define OFF_OP (OFF_VT + NTOK * HS * 2)          // partial O fp16: 256*8*4096*2
#define OFF_ML (OFF_OP + 256 * 8 * 4096 * 2)     // m,l fp32: 256*8*128*4
#define WS_NEED (OFF_ML + 256 * 8 * 128 * 4)     // ~24.4 MB

// ---------------------------------------------------------------------------
// Pack Wq/Wk/Wv (fp32 [768][64]) into MFMA B-fragment order, fp16.
// ---------------------------------------------------------------------------
__global__ __launch_bounds__(256) void pack_w(const float* __restrict__ Wk,
                                              const float* __restrict__ Wq,
                                              const float* __restrict__ Wv,
                                              f16* __restrict__ wpk) {
  int tid = blockIdx.x * 256 + threadIdx.x;      // 72*256 = 18432 exactly
  int mu = tid / (KSTEPS * 256);
  int rem = tid % (KSTEPS * 256);
  int kstep = rem >> 8;
  int ct = (rem >> 6) & 3;
  int lane = rem & 63;
  int col = ct * 16 + (lane & 15);
  int k0 = kstep * 32 + (lane >> 4) * 8;
  const float* src = (mu == 0) ? Wq : ((mu == 1) ? Wk : Wv);
  float scale = (mu == 0) ? 0.125f : 1.0f;
  float t0[8];
#pragma unroll
  for (int j = 0; j < 8; j++) t0[j] = src[(k0 + j) * HS + col];
  f16x8 v;
#pragma unroll
  for (int j = 0; j < 8; j++) v[j] = (f16)(t0[j] * scale);
  *((f16x8*)wpk + tid) = v;
}

// ---------------------------------------------------------------------------
// QKV projection, N-split + software-pipelined K-loop: B-fragments for kstep
// ks+1 are loaded while MFMAs for ks run (double-banked bA/bB), so global
// latency is covered by compute instead of exposed at the top of each step.
// ---------------------------------------------------------------------------
#define BLOAD(DST, KS) do { \
  DST[0] = wpk[((mu0 * KSTEPS + (KS)) * 4 + ct0) * 64 + lane]; \
  DST[1] = wpk[((mu1 * KSTEPS + (KS)) * 4 + ct1) * 64 + lane]; \
  DST[2] = wpk[((mu2 * KSTEPS + (KS)) * 4 + ct2) * 64 + lane]; \
} while (0)

__global__ __launch_bounds__(256) void proj(const float* __restrict__ x,
                                            const f16x8* __restrict__ wpk,
                                            f16* __restrict__ qb,
                                            f16* __restrict__ kb,
                                            f16* __restrict__ vtb) {
  __shared__ __align__(16) f16 xt[16][776];      // 24832 B
  int t = threadIdx.x;
  int w = t >> 6, lane = t & 63, l15 = lane & 15, quad = lane >> 4;
  int r0 = blockIdx.x * 16;
  const float* xbase = x + (size_t)r0 * N_EMBD;
  {
    f32x4 v[12];
#pragma unroll
    for (int i = 0; i < 12; i++)
      v[i] = *(const f32x4*)(xbase + (size_t)(i * 256 + t) * 4);
#pragma unroll
    for (int i = 0; i < 12; i++) {
      int f = i * 256 + t;
      int row = f / 192, cf = f - row * 192;
      f16x4 h;
#pragma unroll
      for (int j = 0; j < 4; j++) h[j] = (f16)v[i][j];
      *(f16x4*)&xt[row][cf * 4] = h;
    }
  }
  __syncthreads();

  f32x4 acc[3];
#pragma unroll
  for (int i = 0; i < 3; i++) acc[i] = (f32x4)0.0f;
  int j0 = w * 3;
  int mu0 = (j0 + 0) >> 2, ct0 = (j0 + 0) & 3;
  int mu1 = (j0 + 1) >> 2, ct1 = (j0 + 1) & 3;
  int mu2 = (j0 + 2) >> 2, ct2 = (j0 + 2) & 3;

  f16x8 bA[3], bB[3];
  BLOAD(bA, 0);
  for (int ks = 0; ks < KSTEPS; ks += 2) {
    f16x8 af0 = *(const f16x8*)&xt[l15][ks * 32 + quad * 8];
    f16x8 af1 = *(const f16x8*)&xt[l15][ks * 32 + 32 + quad * 8];
    BLOAD(bB, ks + 1);
    acc[0] = __builtin_amdgcn_mfma_f32_16x16x32_f16(af0, bA[0], acc[0], 0, 0, 0);
    acc[1] = __builtin_amdgcn_mfma_f32_16x16x32_f16(af0, bA[1], acc[1], 0, 0, 0);
    acc[2] = __builtin_amdgcn_mfma_f32_16x16x32_f16(af0, bA[2], acc[2], 0, 0, 0);
    if (ks + 2 < KSTEPS) BLOAD(bA, ks + 2);
    acc[0] = __builtin_amdgcn_mfma_f32_16x16x32_f16(af1, bB[0], acc[0], 0, 0, 0);
    acc[1] = __builtin_amdgcn_mfma_f32_16x16x32_f16(af1, bB[1], acc[1], 0, 0, 0);
    acc[2] = __builtin_amdgcn_mfma_f32_16x16x32_f16(af1, bB[2], acc[2], 0, 0, 0);
  }
  // C/D layout: col = l15, row = quad*4 + reg
#pragma unroll
  for (int jj = 0; jj < 3; jj++) {
    int j = j0 + jj, mu = j >> 2, ct = j & 3;
    int col = ct * 16 + l15;
    if (mu < 2) {
      f16* dst = mu ? kb : qb;
#pragma unroll
      for (int reg = 0; reg < 4; reg++)
        dst[(r0 + quad * 4 + reg) * HS + col] = (f16)acc[jj][reg];
    } else {
#pragma unroll
      for (int reg = 0; reg < 4; reg++) {
        int row = r0 + quad * 4 + reg;
        vtb[(((row >> 12) * HS + col) << 12) + (row & (SEQ - 1))] = (f16)acc[jj][reg];
      }
    }
  }
}

// ---------------------------------------------------------------------------
// Flash attention partials, software-pipelined:
//   iter i issues: V(i) loads, then K(i+1) prefetch, then S-MFMA (waits only
//   K(i) via vmcnt(16)), softmax (covers V latency), P->LDS, PV (vmcnt(8):
//   waits V(i) but NOT K(i+1) thanks to in-order vmcnt accounting).
// P is converted to f16 and written to LDS inside the exp loop (no pv[4][4]).
// ---------------------------------------------------------------------------
#define KLOAD(DST, KBK) do { \
  int _k0 = (KBK) * 64; \
  _Pragma("unroll") \
  for (int _ks = 0; _ks < 2; _ks++) \
    _Pragma("unroll") \
    for (int _kt = 0; _kt < 4; _kt++) \
      DST[_ks][_kt] = *(const f16x8*)(kb_b + (size_t)(_k0 + _kt * 16 + l15) * HS + _ks * 32 + quad * 8); \
} while (0)

#define ATTN_STEP(KC, KN, KBK, DOPF) do { \
  const int _key0 = (KBK) * 64; \
  f16x8 _vf[2][4]; \
  _Pragma("unroll") \
  for (int _ks = 0; _ks < 2; _ks++) \
    _Pragma("unroll") \
    for (int _dt = 0; _dt < 4; _dt++) \
      _vf[_ks][_dt] = *(const f16x8*)(vt_b + (size_t)(_dt * 16 + l15) * SEQ + _key0 + _ks * 32 + quad * 8); \
  if (DOPF) { KLOAD(KN, (KBK) + 1); } \
  f32x4 _sc[4]; \
  _Pragma("unroll") for (int _kt = 0; _kt < 4; _kt++) _sc[_kt] = (f32x4)0.0f; \
  _Pragma("unroll") \
  for (int _ks = 0; _ks < 2; _ks++) \
    _Pragma("unroll") \
    for (int _kt = 0; _kt < 4; _kt++) \
      _sc[_kt] = __builtin_amdgcn_mfma_f32_16x16x32_f16(KC[_ks][_kt], qa[_ks], _sc[_kt], 0, 0, 0); \
  if ((KBK) == qt) { \
    _Pragma("unroll") \
    for (int _kt = 0; _kt < 4; _kt++) { \
      int _keyb = _key0 + _kt * 16 + quad * 4; \
      _Pragma("unroll") \
      for (int _r = 0; _r < 4; _r++) \
        if (_keyb + _r > qrow) _sc[_kt][_r] = -INFINITY; \
    } \
  } \
  float _mx; \
  { float _a0 = fmaxf(fmaxf(_sc[0][0], _sc[0][1]), fmaxf(_sc[0][2], _sc[0][3])); \
    float _a1 = fmaxf(fmaxf(_sc[1][0], _sc[1][1]), fmaxf(_sc[1][2], _sc[1][3])); \
    float _a2 = fmaxf(fmaxf(_sc[2][0], _sc[2][1]), fmaxf(_sc[2][2], _sc[2][3])); \
    float _a3 = fmaxf(fmaxf(_sc[3][0], _sc[3][1]), fmaxf(_sc[3][2], _sc[3][3])); \
    _mx = fmaxf(fmaxf(_a0, _a1), fmaxf(_a2, _a3)); } \
  _mx = fmaxf(_mx, __shfl_xor(_mx, 16, 64)); \
  _mx = fmaxf(_mx, __shfl_xor(_mx, 32, 64)); \
  float _mn = fmaxf(m, _mx); \
  float _alpha = __expf(m - _mn); \
  m = _mn; \
  float _sum = 0.0f; \
  _Pragma("unroll") \
  for (int _kt = 0; _kt < 4; _kt++) { \
    float _s0 = __expf(_sc[_kt][0] - _mn), _s1 = __expf(_sc[_kt][1] - _mn); \
    float _s2 = __expf(_sc[_kt][2] - _mn), _s3 = __expf(_sc[_kt][3] - _mn); \
    f16x4 _h; _h[0] = (f16)_s0; _h[1] = (f16)_s1; _h[2] = (f16)_s2; _h[3] = (f16)_s3; \
    *(f16x4*)&pbuf[w][l15][_kt * 16 + quad * 4] = _h; \
    _sum += (_s0 + _s1) + (_s2 + _s3); } \
  _sum += __shfl_xor(_sum, 16, 64); \
  _sum += __shfl_xor(_sum, 32, 64); \
  l = l * _alpha + _sum; \
  _Pragma("unroll") for (int _dt = 0; _dt < 4; _dt++) o[_dt] *= _alpha; \
  _Pragma("unroll") \
  for (int _ks = 0; _ks < 2; _ks++) { \
    f16x8 _pf = *(const f16x8*)&pbuf[w][l15][_ks * 32 + quad * 8]; \
    _Pragma("unroll") \
    for (int _dt = 0; _dt < 4; _dt++) \
      o[_dt] = __builtin_amdgcn_mfma_f32_16x16x32_f16(_vf[_ks][_dt], _pf, o[_dt], 0, 0, 0); } \
} while (0)

__global__ __launch_bounds__(256) void attn_part(const f16* __restrict__ qb,
                                                 const f16* __restrict__ kb,
                                                 const f16* __restrict__ vtb,
                                                 f16* __restrict__ opart,
                                                 float* __restrict__ ml) {
  __shared__ __align__(16) f16 pbuf[4][16][72];
  int w = threadIdx.x >> 6, lane = threadIdx.x & 63;
  int l15 = lane & 15, quad = lane >> 4;
  int p = 287 - blockIdx.x, b = blockIdx.y;      // longest (big g) first
  int g = 0;
  while (p >= 4 * (g + 1) * (g + 2)) g++;        // group g: qt in [8g, 8g+8)
  int rem = p - 4 * g * (g + 1);
  int j = rem / (g + 1);
  int s = rem - j * (g + 1);
  int qt = 8 * g + j;
  int kb_beg = s * 8;
  int kb_end = (s * 8 + 8 < qt + 1) ? (s * 8 + 8) : (qt + 1);
  int len = kb_end - kb_beg;

  int qr0 = qt * 64 + w * 16;
  int gq = b * SEQ + qr0;
  int qrow = qr0 + l15;                          // this lane's q-row

  f16x8 qa[2];
  {
    const f16* qrp = qb + (size_t)(gq + l15) * HS + quad * 8;
    qa[0] = *(const f16x8*)(qrp);
    qa[1] = *(const f16x8*)(qrp + 32);
  }

  f32x4 o[4];
#pragma unroll
  for (int i = 0; i < 4; i++) o[i] = (f32x4)0.0f;
  float m = -INFINITY, l = 0.0f;

  const f16* kb_b = kb + (size_t)b * SEQ * HS;
  const f16* vt_b = vtb + (size_t)b * HS * SEQ;

  f16x8 kA[2][4], kB[2][4];
  KLOAD(kA, kb_beg);
  int i = 0;
  for (; i + 2 <= len; i += 2) {
    ATTN_STEP(kA, kB, kb_beg + i, 1);
    ATTN_STEP(kB, kA, kb_beg + i + 1, (i + 2 < len));
  }
  if (i < len) ATTN_STEP(kA, kB, kb_beg + i, 0);

  // store partials: dim = dt*16+quad*4+reg, qrow = w*16+l15
  int slot = (b * 64 + qt) * 8 + s;
  f16* op = opart + (size_t)slot * 4096;
#pragma unroll
  for (int dt = 0; dt < 4; dt++) {
    f16x4 h;
#pragma unroll
    for (int reg = 0; reg < 4; reg++) h[reg] = (f16)o[dt][reg];
    *(f16x4*)&op[(w * 16 + l15) * 64 + dt * 16 + quad * 4] = h;
  }
  if (quad == 0) {
    ml[slot * 128 + w * 16 + l15] = m;
    ml[slot * 128 + 64 + w * 16 + l15] = l;
  }
}

// ---------------------------------------------------------------------------
// Combine: 512 blocks; segment O-loads batched 4-wide.
// ---------------------------------------------------------------------------
__global__ __launch_bounds__(256) void attn_combine(const f16* __restrict__ opart,
                                                    const float* __restrict__ ml,
                                                    float* __restrict__ out) {
  int blk = blockIdx.x;
  int h = blk & 1, bq = blk >> 1;
  int b = bq >> 6, qt = bq & 63;
  int nseg = (qt >> 3) + 1;
  int tid = threadIdx.x;
  int r = h * 32 + (tid >> 3), d0 = (tid & 7) * 8;
  int base_slot = (b * 64 + qt) * 8;

  float mv[8], lv[8];
#pragma unroll
  for (int s = 0; s < 8; s++) {
    if (s < nseg) {
      mv[s] = ml[(base_slot + s) * 128 + r];
      lv[s] = ml[(base_slot + s) * 128 + 64 + r];
    } else { mv[s] = -INFINITY; lv[s] = 0.0f; }
  }
  float M = -INFINITY;
#pragma unroll
  for (int s = 0; s < 8; s++) M = fmaxf(M, mv[s]);
  float e[8], L = 0.0f;
#pragma unroll
  for (int s = 0; s < 8; s++) { e[s] = __expf(mv[s] - M); L += lv[s] * e[s]; }
  float acc[8];
#pragma unroll
  for (int i = 0; i < 8; i++) acc[i] = 0.0f;
  const f16* obase = opart + (size_t)base_slot * 4096 + r * 64 + d0;
  int s = 0;
  for (; s + 4 <= nseg; s += 4) {
    f16x8 a0 = *(const f16x8*)(obase + (size_t)(s + 0) * 4096);
    f16x8 a1 = *(const f16x8*)(obase + (size_t)(s + 1) * 4096);
    f16x8 a2 = *(const f16x8*)(obase + (size_t)(s + 2) * 4096);
    f16x8 a3 = *(const f16x8*)(obase + (size_t)(s + 3) * 4096);
#pragma unroll
    for (int i = 0; i < 8; i++)
      acc[i] += e[s] * (float)a0[i] + e[s + 1] * (float)a1[i] +
                e[s + 2] * (float)a2[i] + e[s + 3] * (float)a3[i];
  }
  for (; s < nseg; s++) {
    f16x8 a = *(const f16x8*)(obase + (size_t)s * 4096);
#pragma unroll
    for (int i = 0; i < 8; i++) acc[i] += e[s] * (float)a[i];
  }
  float inv = 1.0f / L;
  float* po = out + ((size_t)(b * SEQ + qt * 64 + r)) * HS + d0;
#pragma unroll
  for (int i = 0; i < 8; i++) po[i] = acc[i] * inv;
}

// ---------------------------------------------------------------------------
// Fallback monolithic attention (used only if ws_size < WS_NEED).
// ---------------------------------------------------------------------------
__global__ __launch_bounds__(256) void attn_mono(const f16* __restrict__ qb,
                                                 const f16* __restrict__ kb,
                                                 const f16* __restrict__ vtb,
                                                 float* __restrict__ out) {
  __shared__ __align__(16) f16 pbuf[4][16][72];
  int w = threadIdx.x >> 6, lane = threadIdx.x & 63;
  int l15 = lane & 15, quad = lane >> 4;
  int qt = blockIdx.x, b = blockIdx.y;
  int qr0 = qt * 64 + w * 16;
  int gq = b * SEQ + qr0;
  int qrow = qr0 + l15;
  f16x8 qa[2];
  {
    const f16* qrp = qb + (size_t)(gq + l15) * HS + quad * 8;
    qa[0] = *(const f16x8*)(qrp);
    qa[1] = *(const f16x8*)(qrp + 32);
  }
  f32x4 o[4];
#pragma unroll
  for (int i = 0; i < 4; i++) o[i] = (f32x4)0.0f;
  float m = -INFINITY, l = 0.0f;
  const f16* kb_b = kb + (size_t)b * SEQ * HS;
  const f16* vt_b = vtb + (size_t)b * HS * SEQ;
  int len = qt + 1;
  f16x8 kA[2][4], kB[2][4];
  KLOAD(kA, 0);
  int i = 0;
  for (; i + 2 <= len; i += 2) {
    ATTN_STEP(kA, kB, i, 1);
    ATTN_STEP(kB, kA, i + 1, (i + 2 < len));
  }
  if (i < len) ATTN_STEP(kA, kB, i, 0);
  float inv = 1.0f / l;
#pragma unroll
  for (int dt = 0; dt < 4; dt++)
#pragma unroll
    for (int reg = 0; reg < 4; reg++)
      out[(size_t)(b * SEQ + qr0 + l15) * HS + dt * 16 + quad * 4 + reg] = o[dt][reg] * inv;
}

extern "C" void kernel_launch(void* const* d_in, const int* in_sizes, int n_in,
                              void* d_out, int out_size, void* d_ws, size_t ws_size,
                              hipStream_t stream) {
  const float* x  = (const float*)d_in[0];
  const float* Wk = (const float*)d_in[1];
  const float* Wq = (const float*)d_in[2];
  const float* Wv = (const float*)d_in[3];
  float* out = (float*)d_out;

  f16* wpk = (f16*)d_ws;
  f16* qb  = (f16*)((char*)d_ws + OFF_Q);
  f16* kbf = (f16*)((char*)d_ws + OFF_K);
  f16* vtb = (f16*)((char*)d_ws + OFF_VT);
  f16* opart = (f16*)((char*)d_ws + OFF_OP);
  float* ml = (float*)((char*)d_ws + OFF_ML);

  pack_w<<<dim3(72), dim3(256), 0, stream>>>(Wk, Wq, Wv, wpk);
  proj<<<dim3(NTOK / 16), dim3(256), 0, stream>>>(x, (const f16x8*)wpk, qb, kbf, vtb);
  if (ws_size >= (size_t)WS_NEED) {
    attn_part<<<dim3(288, NB), dim3(256), 0, stream>>>(qb, kbf, vtb, opart, ml);
    attn_combine<<<dim3(512), dim3(256), 0, stream>>>(opart, ml, out);
  } else {
    attn_mono<<<dim3(SEQ / 64, NB), dim3(256), 0, stream>>>(qb, kbf, vtb, out);
  }
}

// Round 6
// 179.495 us; speedup vs baseline: 1.0001x; 1.0001x over previous
//
#include <hip/hip_runtime.h>

typedef _Float16 f16;
typedef f16 f16x4 __attribute__((ext_vector_type(4)));
typedef f16 f16x8 __attribute__((ext_vector_type(8)));
typedef float f32x4 __attribute__((ext_vector_type(4)));

#define N_EMBD 768
#define HS 64
#define NB 4
#define SEQ 4096
#define NTOK (NB * SEQ)
#define KSTEPS (N_EMBD / 32)   // 24

// ws layout (bytes)
#define OFF_Q  (3 * KSTEPS * 4 * 64 * 16)        // packed weights: 294912
#define OFF_K  (OFF_Q + NTOK * HS * 2)
#define OFF_VT (OFF_K + NTOK * HS * 2)
#define OFF_OP (OFF_VT + NTOK * HS * 2)          // partial O fp16: 256*8*4096*2
#define OFF_ML (OFF_OP + 256 * 8 * 4096 * 2)     // m,l fp32: 256*8*128*4
#define WS_NEED (OFF_ML + 256 * 8 * 128 * 4)     // ~24.4 MB

// ---------------------------------------------------------------------------
// Pack Wq/Wk/Wv (fp32 [768][64]) into MFMA B-fragment order, fp16.
// ---------------------------------------------------------------------------
__global__ __launch_bounds__(256) void pack_w(const float* __restrict__ Wk,
                                              const float* __restrict__ Wq,
                                              const float* __restrict__ Wv,
                                              f16* __restrict__ wpk) {
  int tid = blockIdx.x * 256 + threadIdx.x;      // 72*256 = 18432 exactly
  int mu = tid / (KSTEPS * 256);
  int rem = tid % (KSTEPS * 256);
  int kstep = rem >> 8;
  int ct = (rem >> 6) & 3;
  int lane = rem & 63;
  int col = ct * 16 + (lane & 15);
  int k0 = kstep * 32 + (lane >> 4) * 8;
  const float* src = (mu == 0) ? Wq : ((mu == 1) ? Wk : Wv);
  float scale = (mu == 0) ? 0.125f : 1.0f;
  float t0[8];
#pragma unroll
  for (int j = 0; j < 8; j++) t0[j] = src[(k0 + j) * HS + col];
  f16x8 v;
#pragma unroll
  for (int j = 0; j < 8; j++) v[j] = (f16)(t0[j] * scale);
  *((f16x8*)wpk + tid) = v;
}

// ---------------------------------------------------------------------------
// QKV projection, N-split. XCD-swizzled: blockIdx%8 -> XCD (round-robin);
// batch b owns XCDs {2b, 2b+1} so q/k/vT stores land in the L2 that the
// attention pass (same binding) will read from.
// ---------------------------------------------------------------------------
__global__ __launch_bounds__(256) void proj(const float* __restrict__ x,
                                            const f16x8* __restrict__ wpk,
                                            f16* __restrict__ qb,
                                            f16* __restrict__ kb,
                                            f16* __restrict__ vtb) {
  __shared__ __align__(16) f16 xt[16][776];      // 24832 B
  int t = threadIdx.x;
  int w = t >> 6, lane = t & 63, l15 = lane & 15, quad = lane >> 4;
  int id = blockIdx.x;                            // 1024 blocks
  int b = (id & 7) >> 1;
  int wb = ((id >> 3) << 1) | (id & 1);           // [0,256) within batch
  int r0 = b * SEQ + wb * 16;
  const float* xbase = x + (size_t)r0 * N_EMBD;
  {
    f32x4 v[12];
#pragma unroll
    for (int i = 0; i < 12; i++)
      v[i] = *(const f32x4*)(xbase + (size_t)(i * 256 + t) * 4);
#pragma unroll
    for (int i = 0; i < 12; i++) {
      int f = i * 256 + t;
      int row = f / 192, cf = f - row * 192;
      f16x4 h;
#pragma unroll
      for (int j = 0; j < 4; j++) h[j] = (f16)v[i][j];
      *(f16x4*)&xt[row][cf * 4] = h;
    }
  }
  __syncthreads();

  f32x4 acc[3];
#pragma unroll
  for (int i = 0; i < 3; i++) acc[i] = (f32x4)0.0f;
  int j0 = w * 3;
  int mu0 = (j0 + 0) >> 2, ct0 = (j0 + 0) & 3;
  int mu1 = (j0 + 1) >> 2, ct1 = (j0 + 1) & 3;
  int mu2 = (j0 + 2) >> 2, ct2 = (j0 + 2) & 3;
  for (int ks = 0; ks < KSTEPS; ks += 2) {
    f16x8 af0 = *(const f16x8*)&xt[l15][ks * 32 + quad * 8];
    f16x8 af1 = *(const f16x8*)&xt[l15][ks * 32 + 32 + quad * 8];
    f16x8 b00 = wpk[((mu0 * KSTEPS + ks) * 4 + ct0) * 64 + lane];
    f16x8 b01 = wpk[((mu1 * KSTEPS + ks) * 4 + ct1) * 64 + lane];
    f16x8 b02 = wpk[((mu2 * KSTEPS + ks) * 4 + ct2) * 64 + lane];
    f16x8 b10 = wpk[((mu0 * KSTEPS + ks + 1) * 4 + ct0) * 64 + lane];
    f16x8 b11 = wpk[((mu1 * KSTEPS + ks + 1) * 4 + ct1) * 64 + lane];
    f16x8 b12 = wpk[((mu2 * KSTEPS + ks + 1) * 4 + ct2) * 64 + lane];
    acc[0] = __builtin_amdgcn_mfma_f32_16x16x32_f16(af0, b00, acc[0], 0, 0, 0);
    acc[1] = __builtin_amdgcn_mfma_f32_16x16x32_f16(af0, b01, acc[1], 0, 0, 0);
    acc[2] = __builtin_amdgcn_mfma_f32_16x16x32_f16(af0, b02, acc[2], 0, 0, 0);
    acc[0] = __builtin_amdgcn_mfma_f32_16x16x32_f16(af1, b10, acc[0], 0, 0, 0);
    acc[1] = __builtin_amdgcn_mfma_f32_16x16x32_f16(af1, b11, acc[1], 0, 0, 0);
    acc[2] = __builtin_amdgcn_mfma_f32_16x16x32_f16(af1, b12, acc[2], 0, 0, 0);
  }
  // C/D layout: col = l15, row = quad*4 + reg
#pragma unroll
  for (int jj = 0; jj < 3; jj++) {
    int j = j0 + jj, mu = j >> 2, ct = j & 3;
    int col = ct * 16 + l15;
    if (mu < 2) {
      f16* dst = mu ? kb : qb;
#pragma unroll
      for (int reg = 0; reg < 4; reg++)
        dst[(r0 + quad * 4 + reg) * HS + col] = (f16)acc[jj][reg];
    } else {
#pragma unroll
      for (int reg = 0; reg < 4; reg++) {
        int row = r0 + quad * 4 + reg;
        vtb[(((row >> 12) * HS + col) << 12) + (row & (SEQ - 1))] = (f16)acc[jj][reg];
      }
    }
  }
}

// ---------------------------------------------------------------------------
// Flash attention partials (r4 structure: batched K loads, V issued before
// softmax). XCD-swizzled: batch = (blockIdx%8)>>1 so each batch's K/V
// (1.5 MB) stays resident in its 2 XCDs' L2 instead of thrashing all 8.
// ---------------------------------------------------------------------------
__global__ __launch_bounds__(256) void attn_part(const f16* __restrict__ qb,
                                                 const f16* __restrict__ kb,
                                                 const f16* __restrict__ vtb,
                                                 f16* __restrict__ opart,
                                                 float* __restrict__ ml) {
  __shared__ __align__(16) f16 pbuf[4][16][72];
  int w = threadIdx.x >> 6, lane = threadIdx.x & 63;
  int l15 = lane & 15, quad = lane >> 4;
  int id = blockIdx.x;                           // 1152 blocks
  int b = (id & 7) >> 1;                         // batch -> XCD pair {2b,2b+1}
  int p = 287 - (((id >> 3) << 1) | (id & 1));   // longest segments first
  int g = 0;
  while (p >= 4 * (g + 1) * (g + 2)) g++;        // group g: qt in [8g, 8g+8)
  int rem = p - 4 * g * (g + 1);
  int j = rem / (g + 1);
  int s = rem - j * (g + 1);
  int qt = 8 * g + j;
  int kb_beg = s * 8;
  int kb_end = (s * 8 + 8 < qt + 1) ? (s * 8 + 8) : (qt + 1);

  int qr0 = qt * 64 + w * 16;
  int gq = b * SEQ + qr0;
  int qrow = qr0 + l15;                          // this lane's q-row

  f16x8 qa[2];
  {
    const f16* qrp = qb + (size_t)(gq + l15) * HS + quad * 8;
    qa[0] = *(const f16x8*)(qrp);
    qa[1] = *(const f16x8*)(qrp + 32);
  }

  f32x4 o[4];
#pragma unroll
  for (int i = 0; i < 4; i++) o[i] = (f32x4)0.0f;
  float m = -INFINITY, l = 0.0f;

  const f16* kb_b = kb + (size_t)b * SEQ * HS;
  const f16* vt_b = vtb + (size_t)b * HS * SEQ;

  for (int kbk = kb_beg; kbk < kb_end; kbk++) {
    int key0 = kbk * 64;
    // ---- batched K-fragment loads (8 independent) ----
    f16x8 kf[2][4];
#pragma unroll
    for (int ks = 0; ks < 2; ks++)
#pragma unroll
      for (int kt = 0; kt < 4; kt++)
        kf[ks][kt] = *(const f16x8*)(kb_b +
            (size_t)(key0 + kt * 16 + l15) * HS + ks * 32 + quad * 8);
    // ---- S^T = K Q^T ----
    f32x4 sc[4];
#pragma unroll
    for (int kt = 0; kt < 4; kt++) sc[kt] = (f32x4)0.0f;
#pragma unroll
    for (int ks = 0; ks < 2; ks++)
#pragma unroll
      for (int kt = 0; kt < 4; kt++)
        sc[kt] = __builtin_amdgcn_mfma_f32_16x16x32_f16(kf[ks][kt], qa[ks], sc[kt], 0, 0, 0);
    // ---- issue V loads NOW (independent of softmax; latency hidden) ----
    f16x8 vf[2][4];
#pragma unroll
    for (int ks = 0; ks < 2; ks++)
#pragma unroll
      for (int dt = 0; dt < 4; dt++)
        vf[ks][dt] = *(const f16x8*)(vt_b +
            (size_t)(dt * 16 + l15) * SEQ + key0 + ks * 32 + quad * 8);
    // ---- causal mask (diagonal block only): C row = key_local ----
    if (kbk == qt) {
#pragma unroll
      for (int kt = 0; kt < 4; kt++) {
        int keyb = key0 + kt * 16 + quad * 4;
#pragma unroll
        for (int reg = 0; reg < 4; reg++)
          if (keyb + reg > qrow) sc[kt][reg] = -INFINITY;
      }
    }
    // ---- per-lane softmax (16 scores) + 2 cross-half shuffles ----
    float mx;
    {
      float a0 = fmaxf(fmaxf(sc[0][0], sc[0][1]), fmaxf(sc[0][2], sc[0][3]));
      float a1 = fmaxf(fmaxf(sc[1][0], sc[1][1]), fmaxf(sc[1][2], sc[1][3]));
      float a2 = fmaxf(fmaxf(sc[2][0], sc[2][1]), fmaxf(sc[2][2], sc[2][3]));
      float a3 = fmaxf(fmaxf(sc[3][0], sc[3][1]), fmaxf(sc[3][2], sc[3][3]));
      mx = fmaxf(fmaxf(a0, a1), fmaxf(a2, a3));
    }
    mx = fmaxf(mx, __shfl_xor(mx, 16, 64));
    mx = fmaxf(mx, __shfl_xor(mx, 32, 64));
    float mn = fmaxf(m, mx);
    float alpha = __expf(m - mn);
    m = mn;
    float pv[4][4];
    float sum = 0.0f;
#pragma unroll
    for (int kt = 0; kt < 4; kt++) {
      float s0 = __expf(sc[kt][0] - mn), s1 = __expf(sc[kt][1] - mn);
      float s2 = __expf(sc[kt][2] - mn), s3 = __expf(sc[kt][3] - mn);
      pv[kt][0] = s0; pv[kt][1] = s1; pv[kt][2] = s2; pv[kt][3] = s3;
      sum += (s0 + s1) + (s2 + s3);
    }
    sum += __shfl_xor(sum, 16, 64);
    sum += __shfl_xor(sum, 32, 64);
    l = l * alpha + sum;
#pragma unroll
    for (int dt = 0; dt < 4; dt++) o[dt] *= alpha;

    // ---- P^T -> LDS (wave-private, regs = 4 consecutive keys -> b64) ----
#pragma unroll
    for (int kt = 0; kt < 4; kt++) {
      f16x4 h;
#pragma unroll
      for (int reg = 0; reg < 4; reg++) h[reg] = (f16)pv[kt][reg];
      *(f16x4*)&pbuf[w][l15][kt * 16 + quad * 4] = h;
    }
    // ---- O^T += V^T P^T ----
#pragma unroll
    for (int ks = 0; ks < 2; ks++) {
      f16x8 pf = *(const f16x8*)&pbuf[w][l15][ks * 32 + quad * 8];
#pragma unroll
      for (int dt = 0; dt < 4; dt++)
        o[dt] = __builtin_amdgcn_mfma_f32_16x16x32_f16(vf[ks][dt], pf, o[dt], 0, 0, 0);
    }
  }
  // store partials: dim = dt*16+quad*4+reg, qrow = w*16+l15
  int slot = (b * 64 + qt) * 8 + s;
  f16* op = opart + (size_t)slot * 4096;
#pragma unroll
  for (int dt = 0; dt < 4; dt++) {
    f16x4 h;
#pragma unroll
    for (int reg = 0; reg < 4; reg++) h[reg] = (f16)o[dt][reg];
    *(f16x4*)&op[(w * 16 + l15) * 64 + dt * 16 + quad * 4] = h;
  }
  if (quad == 0) {
    ml[slot * 128 + w * 16 + l15] = m;
    ml[slot * 128 + 64 + w * 16 + l15] = l;
  }
}

// ---------------------------------------------------------------------------
// Combine: 512 blocks, XCD-swizzled to the batch's XCD pair so opart/ml are
// read from the L2 that attn_part wrote them to.
// ---------------------------------------------------------------------------
__global__ __launch_bounds__(256) void attn_combine(const f16* __restrict__ opart,
                                                    const float* __restrict__ ml,
                                                    float* __restrict__ out) {
  int id = blockIdx.x;
  int b = (id & 7) >> 1;
  int rest = ((id >> 3) << 1) | (id & 1);        // [0,128)
  int qt = rest >> 1, h = rest & 1;
  int nseg = (qt >> 3) + 1;
  int tid = threadIdx.x;
  int r = h * 32 + (tid >> 3), d0 = (tid & 7) * 8;
  int base_slot = (b * 64 + qt) * 8;

  float mv[8], lv[8];
#pragma unroll
  for (int s = 0; s < 8; s++) {
    if (s < nseg) {
      mv[s] = ml[(base_slot + s) * 128 + r];
      lv[s] = ml[(base_slot + s) * 128 + 64 + r];
    } else { mv[s] = -INFINITY; lv[s] = 0.0f; }
  }
  float M = -INFINITY;
#pragma unroll
  for (int s = 0; s < 8; s++) M = fmaxf(M, mv[s]);
  float e[8], L = 0.0f;
#pragma unroll
  for (int s = 0; s < 8; s++) { e[s] = __expf(mv[s] - M); L += lv[s] * e[s]; }
  float acc[8];
#pragma unroll
  for (int i = 0; i < 8; i++) acc[i] = 0.0f;
  const f16* obase = opart + (size_t)base_slot * 4096 + r * 64 + d0;
  int s = 0;
  for (; s + 4 <= nseg; s += 4) {
    f16x8 a0 = *(const f16x8*)(obase + (size_t)(s + 0) * 4096);
    f16x8 a1 = *(const f16x8*)(obase + (size_t)(s + 1) * 4096);
    f16x8 a2 = *(const f16x8*)(obase + (size_t)(s + 2) * 4096);
    f16x8 a3 = *(const f16x8*)(obase + (size_t)(s + 3) * 4096);
#pragma unroll
    for (int i = 0; i < 8; i++)
      acc[i] += e[s] * (float)a0[i] + e[s + 1] * (float)a1[i] +
                e[s + 2] * (float)a2[i] + e[s + 3] * (float)a3[i];
  }
  for (; s < nseg; s++) {
    f16x8 a = *(const f16x8*)(obase + (size_t)s * 4096);
#pragma unroll
    for (int i = 0; i < 8; i++) acc[i] += e[s] * (float)a[i];
  }
  float inv = 1.0f / L;
  float* po = out + ((size_t)(b * SEQ + qt * 64 + r)) * HS + d0;
#pragma unroll
  for (int i = 0; i < 8; i++) po[i] = acc[i] * inv;
}

// ---------------------------------------------------------------------------
// Fallback monolithic attention (used only if ws_size < WS_NEED).
// ---------------------------------------------------------------------------
__global__ __launch_bounds__(256) void attn_mono(const f16* __restrict__ qb,
                                                 const f16* __restrict__ kb,
                                                 const f16* __restrict__ vtb,
                                                 float* __restrict__ out) {
  __shared__ __align__(16) f16 pbuf[4][16][72];
  int w = threadIdx.x >> 6, lane = threadIdx.x & 63;
  int l15 = lane & 15, quad = lane >> 4;
  int qt = blockIdx.x, b = blockIdx.y;
  int qr0 = qt * 64 + w * 16;
  int gq = b * SEQ + qr0;
  int qrow = qr0 + l15;
  f16x8 qa[2];
  {
    const f16* qrp = qb + (size_t)(gq + l15) * HS + quad * 8;
    qa[0] = *(const f16x8*)(qrp);
    qa[1] = *(const f16x8*)(qrp + 32);
  }
  f32x4 o[4];
#pragma unroll
  for (int i = 0; i < 4; i++) o[i] = (f32x4)0.0f;
  float m = -INFINITY, l = 0.0f;
  const f16* kb_b = kb + (size_t)b * SEQ * HS;
  const f16* vt_b = vtb + (size_t)b * HS * SEQ;
  for (int kbk = 0; kbk <= qt; kbk++) {
    int key0 = kbk * 64;
    f16x8 kf[2][4];
#pragma unroll
    for (int ks = 0; ks < 2; ks++)
#pragma unroll
      for (int kt = 0; kt < 4; kt++)
        kf[ks][kt] = *(const f16x8*)(kb_b +
            (size_t)(key0 + kt * 16 + l15) * HS + ks * 32 + quad * 8);
    f32x4 sc[4];
#pragma unroll
    for (int kt = 0; kt < 4; kt++) sc[kt] = (f32x4)0.0f;
#pragma unroll
    for (int ks = 0; ks < 2; ks++)
#pragma unroll
      for (int kt = 0; kt < 4; kt++)
        sc[kt] = __builtin_amdgcn_mfma_f32_16x16x32_f16(kf[ks][kt], qa[ks], sc[kt], 0, 0, 0);
    f16x8 vf[2][4];
#pragma unroll
    for (int ks = 0; ks < 2; ks++)
#pragma unroll
      for (int dt = 0; dt < 4; dt++)
        vf[ks][dt] = *(const f16x8*)(vt_b +
            (size_t)(dt * 16 + l15) * SEQ + key0 + ks * 32 + quad * 8);
    if (kbk == qt) {
#pragma unroll
      for (int kt = 0; kt < 4; kt++) {
        int keyb = key0 + kt * 16 + quad * 4;
#pragma unroll
        for (int reg = 0; reg < 4; reg++)
          if (keyb + reg > qrow) sc[kt][reg] = -INFINITY;
      }
    }
    float mx;
    {
      float a0 = fmaxf(fmaxf(sc[0][0], sc[0][1]), fmaxf(sc[0][2], sc[0][3]));
      float a1 = fmaxf(fmaxf(sc[1][0], sc[1][1]), fmaxf(sc[1][2], sc[1][3]));
      float a2 = fmaxf(fmaxf(sc[2][0], sc[2][1]), fmaxf(sc[2][2], sc[2][3]));
      float a3 = fmaxf(fmaxf(sc[3][0], sc[3][1]), fmaxf(sc[3][2], sc[3][3]));
      mx = fmaxf(fmaxf(a0, a1), fmaxf(a2, a3));
    }
    mx = fmaxf(mx, __shfl_xor(mx, 16, 64));
    mx = fmaxf(mx, __shfl_xor(mx, 32, 64));
    float mn = fmaxf(m, mx);
    float alpha = __expf(m - mn);
    m = mn;
    float pv[4][4];
    float sum = 0.0f;
#pragma unroll
    for (int kt = 0; kt < 4; kt++) {
      float s0 = __expf(sc[kt][0] - mn), s1 = __expf(sc[kt][1] - mn);
      float s2 = __expf(sc[kt][2] - mn), s3 = __expf(sc[kt][3] - mn);
      pv[kt][0] = s0; pv[kt][1] = s1; pv[kt][2] = s2; pv[kt][3] = s3;
      sum += (s0 + s1) + (s2 + s3);
    }
    sum += __shfl_xor(sum, 16, 64);
    sum += __shfl_xor(sum, 32, 64);
    l = l * alpha + sum;
#pragma unroll
    for (int dt = 0; dt < 4; dt++) o[dt] *= alpha;
#pragma unroll
    for (int kt = 0; kt < 4; kt++) {
      f16x4 hh;
#pragma unroll
      for (int reg = 0; reg < 4; reg++) hh[reg] = (f16)pv[kt][reg];
      *(f16x4*)&pbuf[w][l15][kt * 16 + quad * 4] = hh;
    }
#pragma unroll
    for (int ks = 0; ks < 2; ks++) {
      f16x8 pf = *(const f16x8*)&pbuf[w][l15][ks * 32 + quad * 8];
#pragma unroll
      for (int dt = 0; dt < 4; dt++)
        o[dt] = __builtin_amdgcn_mfma_f32_16x16x32_f16(vf[ks][dt], pf, o[dt], 0, 0, 0);
    }
  }
  float inv = 1.0f / l;
#pragma unroll
  for (int dt = 0; dt < 4; dt++)
#pragma unroll
    for (int reg = 0; reg < 4; reg++)
      out[(size_t)(b * SEQ + qr0 + l15) * HS + dt * 16 + quad * 4 + reg] = o[dt][reg] * inv;
}

extern "C" void kernel_launch(void* const* d_in, const int* in_sizes, int n_in,
                              void* d_out, int out_size, void* d_ws, size_t ws_size,
                              hipStream_t stream) {
  const float* x  = (const float*)d_in[0];
  const float* Wk = (const float*)d_in[1];
  const float* Wq = (const float*)d_in[2];
  const float* Wv = (const float*)d_in[3];
  float* out = (float*)d_out;

  f16* wpk = (f16*)d_ws;
  f16* qb  = (f16*)((char*)d_ws + OFF_Q);
  f16* kbf = (f16*)((char*)d_ws + OFF_K);
  f16* vtb = (f16*)((char*)d_ws + OFF_VT);
  f16* opart = (f16*)((char*)d_ws + OFF_OP);
  float* ml = (float*)((char*)d_ws + OFF_ML);

  pack_w<<<dim3(72), dim3(256), 0, stream>>>(Wk, Wq, Wv, wpk);
  proj<<<dim3(NTOK / 16), dim3(256), 0, stream>>>(x, (const f16x8*)wpk, qb, kbf, vtb);
  if (ws_size >= (size_t)WS_NEED) {
    attn_part<<<dim3(288 * NB), dim3(256), 0, stream>>>(qb, kbf, vtb, opart, ml);
    attn_combine<<<dim3(512), dim3(256), 0, stream>>>(opart, ml, out);
  } else {
    attn_mono<<<dim3(SEQ / 64, NB), dim3(256), 0, stream>>>(qb, kbf, vtb, out);
  }
}

// Round 7
// 129.332 us; speedup vs baseline: 1.3881x; 1.3879x over previous
//
#include <hip/hip_runtime.h>

typedef _Float16 f16;
typedef f16 f16x4 __attribute__((ext_vector_type(4)));
typedef f16 f16x8 __attribute__((ext_vector_type(8)));
typedef float f32x4 __attribute__((ext_vector_type(4)));

#define N_EMBD 768
#define HS 64
#define NB 4
#define SEQ 4096
#define NTOK (NB * SEQ)
#define KSTEPS (N_EMBD / 32)   // 24

// ws layout (bytes)
#define OFF_Q  (3 * KSTEPS * 4 * 64 * 16)        // packed weights: 294912
#define OFF_KV (OFF_Q + NTOK * HS * 2)           // q fp16: 2 MB
#define OFF_OP (OFF_KV + NB * 64 * 16384)        // kv tiles: 4 MB
#define OFF_ML (OFF_OP + 2048 * 4096 * 2)        // opart: 16 MB
#define WS_NEED (OFF_ML + 2048 * 128 * 4)        // + ml 1 MB

// ---------------------------------------------------------------------------
// Pack Wq/Wk/Wv (fp32 [768][64]) into MFMA B-fragment order, fp16.
// ---------------------------------------------------------------------------
__global__ __launch_bounds__(256) void pack_w(const float* __restrict__ Wk,
                                              const float* __restrict__ Wq,
                                              const float* __restrict__ Wv,
                                              f16* __restrict__ wpk) {
  int tid = blockIdx.x * 256 + threadIdx.x;      // 72*256 = 18432 exactly
  int mu = tid / (KSTEPS * 256);
  int rem = tid % (KSTEPS * 256);
  int kstep = rem >> 8;
  int ct = (rem >> 6) & 3;
  int lane = rem & 63;
  int col = ct * 16 + (lane & 15);
  int k0 = kstep * 32 + (lane >> 4) * 8;
  const float* src = (mu == 0) ? Wq : ((mu == 1) ? Wk : Wv);
  float scale = (mu == 0) ? 0.125f : 1.0f;
  float t0[8];
#pragma unroll
  for (int j = 0; j < 8; j++) t0[j] = src[(k0 + j) * HS + col];
  f16x8 v;
#pragma unroll
  for (int j = 0; j < 8; j++) v[j] = (f16)(t0[j] * scale);
  *((f16x8*)wpk + tid) = v;
}

// ---------------------------------------------------------------------------
// QKV projection. Q -> qb [tok][64]. K,V -> fragment-plane tiled layout:
// per (batch, 64-key tile): 16 planes x 1 KB (16 KB). Plane pk=ks*4+kt holds
// K-frag image (lane L: K[kt*16+(L&15)][ks*32+(L>>4)*8+j]); plane 8+ks*4+dt
// holds V^T-frag image (lane L: V[ks*32+(L>>4)*8+j][dt*16+(L&15)]).
// A straight 16 KB contiguous copy of a tile into LDS then gives conflict-
// free ds_read_b128 fragment reads at base+lane*16 in the attention kernel.
// ---------------------------------------------------------------------------
__global__ __launch_bounds__(256) void proj(const float* __restrict__ x,
                                            const f16x8* __restrict__ wpk,
                                            f16* __restrict__ qb,
                                            f16* __restrict__ kvt) {
  __shared__ __align__(16) f16 xt[16][776];      // 24832 B
  __shared__ __align__(16) f16 klds[16][72];
  __shared__ __align__(16) f16 vlds[16][72];
  int t = threadIdx.x;
  int w = t >> 6, lane = t & 63, l15 = lane & 15, quad = lane >> 4;
  int id = blockIdx.x;                            // 1024 blocks
  int b = (id & 7) >> 1;                          // XCD pair binding
  int wb = ((id >> 3) << 1) | (id & 1);           // [0,256) within batch
  int tt = wb >> 2, kt = wb & 3;                  // key-tile, 16-key slice
  int r0 = b * SEQ + wb * 16;
  const float* xbase = x + (size_t)r0 * N_EMBD;
  {
    f32x4 v[12];
#pragma unroll
    for (int i = 0; i < 12; i++)
      v[i] = *(const f32x4*)(xbase + (size_t)(i * 256 + t) * 4);
#pragma unroll
    for (int i = 0; i < 12; i++) {
      int f = i * 256 + t;
      int row = f / 192, cf = f - row * 192;
      f16x4 h;
#pragma unroll
      for (int j = 0; j < 4; j++) h[j] = (f16)v[i][j];
      *(f16x4*)&xt[row][cf * 4] = h;
    }
  }
  __syncthreads();

  f32x4 acc[3];
#pragma unroll
  for (int i = 0; i < 3; i++) acc[i] = (f32x4)0.0f;
  int j0 = w * 3;
  int mu0 = (j0 + 0) >> 2, ct0 = (j0 + 0) & 3;
  int mu1 = (j0 + 1) >> 2, ct1 = (j0 + 1) & 3;
  int mu2 = (j0 + 2) >> 2, ct2 = (j0 + 2) & 3;
  for (int ks = 0; ks < KSTEPS; ks += 2) {
    f16x8 af0 = *(const f16x8*)&xt[l15][ks * 32 + quad * 8];
    f16x8 af1 = *(const f16x8*)&xt[l15][ks * 32 + 32 + quad * 8];
    f16x8 b00 = wpk[((mu0 * KSTEPS + ks) * 4 + ct0) * 64 + lane];
    f16x8 b01 = wpk[((mu1 * KSTEPS + ks) * 4 + ct1) * 64 + lane];
    f16x8 b02 = wpk[((mu2 * KSTEPS + ks) * 4 + ct2) * 64 + lane];
    f16x8 b10 = wpk[((mu0 * KSTEPS + ks + 1) * 4 + ct0) * 64 + lane];
    f16x8 b11 = wpk[((mu1 * KSTEPS + ks + 1) * 4 + ct1) * 64 + lane];
    f16x8 b12 = wpk[((mu2 * KSTEPS + ks + 1) * 4 + ct2) * 64 + lane];
    acc[0] = __builtin_amdgcn_mfma_f32_16x16x32_f16(af0, b00, acc[0], 0, 0, 0);
    acc[1] = __builtin_amdgcn_mfma_f32_16x16x32_f16(af0, b01, acc[1], 0, 0, 0);
    acc[2] = __builtin_amdgcn_mfma_f32_16x16x32_f16(af0, b02, acc[2], 0, 0, 0);
    acc[0] = __builtin_amdgcn_mfma_f32_16x16x32_f16(af1, b10, acc[0], 0, 0, 0);
    acc[1] = __builtin_amdgcn_mfma_f32_16x16x32_f16(af1, b11, acc[1], 0, 0, 0);
    acc[2] = __builtin_amdgcn_mfma_f32_16x16x32_f16(af1, b12, acc[2], 0, 0, 0);
  }
  // C/D layout: col = l15, row = quad*4 + reg. Q direct; K,V via LDS bounce.
#pragma unroll
  for (int jj = 0; jj < 3; jj++) {
    int j = j0 + jj, mu = j >> 2, ct = j & 3;
    if (mu == 0) {
#pragma unroll
      for (int reg = 0; reg < 4; reg++)
        qb[(size_t)(r0 + quad * 4 + reg) * HS + ct * 16 + l15] = (f16)acc[jj][reg];
    } else if (mu == 1) {
#pragma unroll
      for (int reg = 0; reg < 4; reg++)
        klds[quad * 4 + reg][ct * 16 + l15] = (f16)acc[jj][reg];
    } else {
#pragma unroll
      for (int reg = 0; reg < 4; reg++)
        vlds[quad * 4 + reg][ct * 16 + l15] = (f16)acc[jj][reg];
    }
  }
  __syncthreads();
  f16* tbase = kvt + (size_t)(b * 64 + tt) * 8192;
  if (t < 128) {
    int ks = t >> 6, lam = t & 63;
    f16x8 h = *(const f16x8*)&klds[lam & 15][ks * 32 + (lam >> 4) * 8];
    *(f16x8*)(tbase + (ks * 4 + kt) * 512 + lam * 8) = h;
  } else {
    int u = t - 128;
    int dt = u >> 5, w2 = u & 31, rr = w2 >> 4, c = w2 & 15;
    int lam = (2 * (kt & 1) + rr) * 16 + c;
    f16x8 h;
#pragma unroll
    for (int jq = 0; jq < 8; jq++) h[jq] = vlds[rr * 8 + jq][dt * 16 + c];
    *(f16x8*)(tbase + (8 + (kt >> 1) * 4 + dt) * 512 + lam * 8) = h;
  }
}

// ---------------------------------------------------------------------------
// Attention: double-buffered LDS staging of 16 KB K/V tiles via
// global_load_lds (width 16); fragment reads are conflict-free ds_read_b128.
// ---------------------------------------------------------------------------
#define STAGE(BUF, TILE) do { \
  const f16* _s = kv_b + (size_t)(TILE) * 8192 + (size_t)threadIdx.x * 8; \
  _Pragma("unroll") \
  for (int _k = 0; _k < 4; _k++) \
    __builtin_amdgcn_global_load_lds( \
        (const __attribute__((address_space(1))) unsigned int*)(_s + _k * 2048), \
        (__attribute__((address_space(3))) unsigned int*)&(BUF)[_k * 2048 + w * 512], \
        16, 0, 0); \
} while (0)

#define ATTN_STEP(CUR, KBK) do { \
  const int _key0 = (KBK) * 64; \
  f16x8 _kf[2][4]; \
  _Pragma("unroll") \
  for (int _ks = 0; _ks < 2; _ks++) \
    _Pragma("unroll") \
    for (int _kt = 0; _kt < 4; _kt++) \
      _kf[_ks][_kt] = *(const f16x8*)&(CUR)[(_ks * 4 + _kt) * 512 + lane * 8]; \
  f32x4 _sc[4]; \
  _Pragma("unroll") for (int _kt = 0; _kt < 4; _kt++) _sc[_kt] = (f32x4)0.0f; \
  _Pragma("unroll") \
  for (int _ks = 0; _ks < 2; _ks++) \
    _Pragma("unroll") \
    for (int _kt = 0; _kt < 4; _kt++) \
      _sc[_kt] = __builtin_amdgcn_mfma_f32_16x16x32_f16(_kf[_ks][_kt], qa[_ks], _sc[_kt], 0, 0, 0); \
  f16x8 _vf[2][4]; \
  _Pragma("unroll") \
  for (int _ks = 0; _ks < 2; _ks++) \
    _Pragma("unroll") \
    for (int _dt = 0; _dt < 4; _dt++) \
      _vf[_ks][_dt] = *(const f16x8*)&(CUR)[(8 + _ks * 4 + _dt) * 512 + lane * 8]; \
  if ((KBK) == qt) { \
    _Pragma("unroll") \
    for (int _kt = 0; _kt < 4; _kt++) { \
      int _keyb = _key0 + _kt * 16 + quad * 4; \
      _Pragma("unroll") \
      for (int _r = 0; _r < 4; _r++) \
        if (_keyb + _r > qrow) _sc[_kt][_r] = -INFINITY; \
    } \
  } \
  float _mx; \
  { float _a0 = fmaxf(fmaxf(_sc[0][0], _sc[0][1]), fmaxf(_sc[0][2], _sc[0][3])); \
    float _a1 = fmaxf(fmaxf(_sc[1][0], _sc[1][1]), fmaxf(_sc[1][2], _sc[1][3])); \
    float _a2 = fmaxf(fmaxf(_sc[2][0], _sc[2][1]), fmaxf(_sc[2][2], _sc[2][3])); \
    float _a3 = fmaxf(fmaxf(_sc[3][0], _sc[3][1]), fmaxf(_sc[3][2], _sc[3][3])); \
    _mx = fmaxf(fmaxf(_a0, _a1), fmaxf(_a2, _a3)); } \
  _mx = fmaxf(_mx, __shfl_xor(_mx, 16, 64)); \
  _mx = fmaxf(_mx, __shfl_xor(_mx, 32, 64)); \
  float _mn = fmaxf(m, _mx); \
  float _alpha = __expf(m - _mn); \
  m = _mn; \
  float _sum = 0.0f; \
  _Pragma("unroll") \
  for (int _kt = 0; _kt < 4; _kt++) { \
    float _s0 = __expf(_sc[_kt][0] - _mn), _s1 = __expf(_sc[_kt][1] - _mn); \
    float _s2 = __expf(_sc[_kt][2] - _mn), _s3 = __expf(_sc[_kt][3] - _mn); \
    f16x4 _h; _h[0] = (f16)_s0; _h[1] = (f16)_s1; _h[2] = (f16)_s2; _h[3] = (f16)_s3; \
    *(f16x4*)&pbuf[w][l15][_kt * 16 + quad * 4] = _h; \
    _sum += (_s0 + _s1) + (_s2 + _s3); } \
  _sum += __shfl_xor(_sum, 16, 64); \
  _sum += __shfl_xor(_sum, 32, 64); \
  l = l * _alpha + _sum; \
  _Pragma("unroll") for (int _dt = 0; _dt < 4; _dt++) o[_dt] *= _alpha; \
  _Pragma("unroll") \
  for (int _ks = 0; _ks < 2; _ks++) { \
    f16x8 _pf = *(const f16x8*)&pbuf[w][l15][_ks * 32 + quad * 8]; \
    _Pragma("unroll") \
    for (int _dt = 0; _dt < 4; _dt++) \
      o[_dt] = __builtin_amdgcn_mfma_f32_16x16x32_f16(_vf[_ks][_dt], _pf, o[_dt], 0, 0, 0); } \
} while (0)

__global__ __launch_bounds__(256) void attn_part(const f16* __restrict__ qb,
                                                 const f16* __restrict__ kvt,
                                                 f16* __restrict__ opart,
                                                 float* __restrict__ ml) {
  __shared__ __align__(16) f16 kvbuf[2][8192];   // 32 KB double buffer
  __shared__ __align__(16) f16 pbuf[4][16][72];
  int w = threadIdx.x >> 6, lane = threadIdx.x & 63;
  int l15 = lane & 15, quad = lane >> 4;
  int id = blockIdx.x;                           // 1152 blocks
  int b = (id & 7) >> 1;                         // batch -> XCD pair
  int p = 287 - (((id >> 3) << 1) | (id & 1));   // longest segments first
  int g = 0;
  while (p >= 4 * (g + 1) * (g + 2)) g++;
  int rem = p - 4 * g * (g + 1);
  int j = rem / (g + 1);
  int s = rem - j * (g + 1);
  int qt = 8 * g + j;
  int kb_beg = s * 8;
  int kb_end = (s * 8 + 8 < qt + 1) ? (s * 8 + 8) : (qt + 1);

  int qr0 = qt * 64 + w * 16;
  int gq = b * SEQ + qr0;
  int qrow = qr0 + l15;

  const f16* kv_b = kvt + (size_t)b * 64 * 8192;
  STAGE(kvbuf[0], kb_beg);

  f16x8 qa[2];
  {
    const f16* qrp = qb + (size_t)(gq + l15) * HS + quad * 8;
    qa[0] = *(const f16x8*)(qrp);
    qa[1] = *(const f16x8*)(qrp + 32);
  }
  f32x4 o[4];
#pragma unroll
  for (int i = 0; i < 4; i++) o[i] = (f32x4)0.0f;
  float m = -INFINITY, l = 0.0f;

  int cur = 0;
  for (int i = kb_beg; i < kb_end; i++) {
    __syncthreads();                             // staging of cur complete
    if (i + 1 < kb_end) STAGE(kvbuf[cur ^ 1], i + 1);
    ATTN_STEP(kvbuf[cur], i);
    cur ^= 1;
  }

  int slot = (b * 64 + qt) * 8 + s;
  f16* op = opart + (size_t)slot * 4096;
#pragma unroll
  for (int dt = 0; dt < 4; dt++) {
    f16x4 h;
#pragma unroll
    for (int reg = 0; reg < 4; reg++) h[reg] = (f16)o[dt][reg];
    *(f16x4*)&op[(w * 16 + l15) * 64 + dt * 16 + quad * 4] = h;
  }
  if (quad == 0) {
    ml[slot * 128 + w * 16 + l15] = m;
    ml[slot * 128 + 64 + w * 16 + l15] = l;
  }
}

// ---------------------------------------------------------------------------
// Combine: 512 blocks, XCD-swizzled to the batch's XCD pair.
// ---------------------------------------------------------------------------
__global__ __launch_bounds__(256) void attn_combine(const f16* __restrict__ opart,
                                                    const float* __restrict__ ml,
                                                    float* __restrict__ out) {
  int id = blockIdx.x;
  int b = (id & 7) >> 1;
  int rest = ((id >> 3) << 1) | (id & 1);        // [0,128)
  int qt = rest >> 1, h = rest & 1;
  int nseg = (qt >> 3) + 1;
  int tid = threadIdx.x;
  int r = h * 32 + (tid >> 3), d0 = (tid & 7) * 8;
  int base_slot = (b * 64 + qt) * 8;

  float mv[8], lv[8];
#pragma unroll
  for (int s = 0; s < 8; s++) {
    if (s < nseg) {
      mv[s] = ml[(base_slot + s) * 128 + r];
      lv[s] = ml[(base_slot + s) * 128 + 64 + r];
    } else { mv[s] = -INFINITY; lv[s] = 0.0f; }
  }
  float M = -INFINITY;
#pragma unroll
  for (int s = 0; s < 8; s++) M = fmaxf(M, mv[s]);
  float e[8], L = 0.0f;
#pragma unroll
  for (int s = 0; s < 8; s++) { e[s] = __expf(mv[s] - M); L += lv[s] * e[s]; }
  float acc[8];
#pragma unroll
  for (int i = 0; i < 8; i++) acc[i] = 0.0f;
  const f16* obase = opart + (size_t)base_slot * 4096 + r * 64 + d0;
  int s = 0;
  for (; s + 4 <= nseg; s += 4) {
    f16x8 a0 = *(const f16x8*)(obase + (size_t)(s + 0) * 4096);
    f16x8 a1 = *(const f16x8*)(obase + (size_t)(s + 1) * 4096);
    f16x8 a2 = *(const f16x8*)(obase + (size_t)(s + 2) * 4096);
    f16x8 a3 = *(const f16x8*)(obase + (size_t)(s + 3) * 4096);
#pragma unroll
    for (int i = 0; i < 8; i++)
      acc[i] += e[s] * (float)a0[i] + e[s + 1] * (float)a1[i] +
                e[s + 2] * (float)a2[i] + e[s + 3] * (float)a3[i];
  }
  for (; s < nseg; s++) {
    f16x8 a = *(const f16x8*)(obase + (size_t)s * 4096);
#pragma unroll
    for (int i = 0; i < 8; i++) acc[i] += e[s] * (float)a[i];
  }
  float inv = 1.0f / L;
  float* po = out + ((size_t)(b * SEQ + qt * 64 + r)) * HS + d0;
#pragma unroll
  for (int i = 0; i < 8; i++) po[i] = acc[i] * inv;
}

// ---------------------------------------------------------------------------
// Fallback monolithic attention (ws too small for opart/ml).
// ---------------------------------------------------------------------------
__global__ __launch_bounds__(256) void attn_mono(const f16* __restrict__ qb,
                                                 const f16* __restrict__ kvt,
                                                 float* __restrict__ out) {
  __shared__ __align__(16) f16 kvbuf[2][8192];
  __shared__ __align__(16) f16 pbuf[4][16][72];
  int w = threadIdx.x >> 6, lane = threadIdx.x & 63;
  int l15 = lane & 15, quad = lane >> 4;
  int qt = blockIdx.x, b = blockIdx.y;
  int qr0 = qt * 64 + w * 16;
  int gq = b * SEQ + qr0;
  int qrow = qr0 + l15;
  const f16* kv_b = kvt + (size_t)b * 64 * 8192;
  STAGE(kvbuf[0], 0);
  f16x8 qa[2];
  {
    const f16* qrp = qb + (size_t)(gq + l15) * HS + quad * 8;
    qa[0] = *(const f16x8*)(qrp);
    qa[1] = *(const f16x8*)(qrp + 32);
  }
  f32x4 o[4];
#pragma unroll
  for (int i = 0; i < 4; i++) o[i] = (f32x4)0.0f;
  float m = -INFINITY, l = 0.0f;
  int cur = 0;
  for (int i = 0; i <= qt; i++) {
    __syncthreads();
    if (i + 1 <= qt) STAGE(kvbuf[cur ^ 1], i + 1);
    ATTN_STEP(kvbuf[cur], i);
    cur ^= 1;
  }
  float inv = 1.0f / l;
#pragma unroll
  for (int dt = 0; dt < 4; dt++)
#pragma unroll
    for (int reg = 0; reg < 4; reg++)
      out[(size_t)(b * SEQ + qr0 + l15) * HS + dt * 16 + quad * 4 + reg] = o[dt][reg] * inv;
}

extern "C" void kernel_launch(void* const* d_in, const int* in_sizes, int n_in,
                              void* d_out, int out_size, void* d_ws, size_t ws_size,
                              hipStream_t stream) {
  const float* x  = (const float*)d_in[0];
  const float* Wk = (const float*)d_in[1];
  const float* Wq = (const float*)d_in[2];
  const float* Wv = (const float*)d_in[3];
  float* out = (float*)d_out;

  f16* wpk = (f16*)d_ws;
  f16* qb  = (f16*)((char*)d_ws + OFF_Q);
  f16* kvt = (f16*)((char*)d_ws + OFF_KV);
  f16* opart = (f16*)((char*)d_ws + OFF_OP);
  float* ml = (float*)((char*)d_ws + OFF_ML);

  pack_w<<<dim3(72), dim3(256), 0, stream>>>(Wk, Wq, Wv, wpk);
  proj<<<dim3(NTOK / 16), dim3(256), 0, stream>>>(x, (const f16x8*)wpk, qb, kvt);
  if (ws_size >= (size_t)WS_NEED) {
    attn_part<<<dim3(288 * NB), dim3(256), 0, stream>>>(qb, kvt, opart, ml);
    attn_combine<<<dim3(512), dim3(256), 0, stream>>>(opart, ml, out);
  } else {
    attn_mono<<<dim3(SEQ / 64, NB), dim3(256), 0, stream>>>(qb, kvt, out);
  }
}

// Round 8
// 128.306 us; speedup vs baseline: 1.3992x; 1.0080x over previous
//
#include <hip/hip_runtime.h>

typedef _Float16 f16;
typedef f16 f16x4 __attribute__((ext_vector_type(4)));
typedef f16 f16x8 __attribute__((ext_vector_type(8)));
typedef float f32x4 __attribute__((ext_vector_type(4)));

#define N_EMBD 768
#define HS 64
#define NB 4
#define SEQ 4096
#define NTOK (NB * SEQ)
#define KSTEPS (N_EMBD / 32)   // 24

// ws layout (bytes)
#define OFF_Q  (3 * KSTEPS * 4 * 64 * 16)        // packed weights: 294912
#define OFF_KV (OFF_Q + NTOK * HS * 2)           // q fp16: 2 MB
#define OFF_OP (OFF_KV + NB * 64 * 16384)        // kv tiles: 4 MB
#define OFF_ML (OFF_OP + 2048 * 4096 * 2)        // opart: 16 MB
#define WS_NEED (OFF_ML + 2048 * 128 * 4)        // + ml 1 MB

// ---------------------------------------------------------------------------
// Pack Wq/Wk/Wv (fp32 [768][64]) into MFMA B-fragment order, fp16.
// ---------------------------------------------------------------------------
__global__ __launch_bounds__(256) void pack_w(const float* __restrict__ Wk,
                                              const float* __restrict__ Wq,
                                              const float* __restrict__ Wv,
                                              f16* __restrict__ wpk) {
  int tid = blockIdx.x * 256 + threadIdx.x;      // 72*256 = 18432 exactly
  int mu = tid / (KSTEPS * 256);
  int rem = tid % (KSTEPS * 256);
  int kstep = rem >> 8;
  int ct = (rem >> 6) & 3;
  int lane = rem & 63;
  int col = ct * 16 + (lane & 15);
  int k0 = kstep * 32 + (lane >> 4) * 8;
  const float* src = (mu == 0) ? Wq : ((mu == 1) ? Wk : Wv);
  float scale = (mu == 0) ? 0.125f : 1.0f;
  float t0[8];
#pragma unroll
  for (int j = 0; j < 8; j++) t0[j] = src[(k0 + j) * HS + col];
  f16x8 v;
#pragma unroll
  for (int j = 0; j < 8; j++) v[j] = (f16)(t0[j] * scale);
  *((f16x8*)wpk + tid) = v;
}

// ---------------------------------------------------------------------------
// QKV projection v2: 32 tokens/block (512 blocks), 4 waves, each wave owns
// 3 N-tiles applied to 2 row-groups per kstep -> each weight fragment feeds
// 2 MFMAs (halves L2 weight traffic; 12 MFMAs per 3-load chain). K,V go to
// the fragment-plane tiled kvt layout (same as r7) via LDS bounce; V is
// written dim-major (vtl[dim][key], pad 40) so repack reads are b128.
// ---------------------------------------------------------------------------
__global__ __launch_bounds__(256) void proj(const float* __restrict__ x,
                                            const f16x8* __restrict__ wpk,
                                            f16* __restrict__ qb,
                                            f16* __restrict__ kvt) {
  __shared__ __align__(16) f16 xt[32][776];      // 49664 B
  __shared__ __align__(16) f16 klds[32][72];     // 4608 B
  __shared__ __align__(16) f16 vtl[64][40];      // 5120 B
  int t = threadIdx.x;
  int w = t >> 6, lane = t & 63, l15 = lane & 15, quad = lane >> 4;
  int id = blockIdx.x;                            // 512 blocks
  int b = (id & 7) >> 1;                          // XCD pair binding
  int g = ((id >> 3) << 1) | (id & 1);            // [0,128) within batch
  int r0 = b * SEQ + g * 32;
  int tt = g >> 1;                                // 64-key tile
  int h = g & 1;                                  // which half of the tile
  const float* xbase = x + (size_t)r0 * N_EMBD;
  // stage x: 32 tokens x 768 f32 -> fp16 LDS, fully-coalesced float4 loads
#pragma unroll
  for (int half = 0; half < 2; half++) {
    f32x4 v[12];
#pragma unroll
    for (int i = 0; i < 12; i++)
      v[i] = *(const f32x4*)(xbase + (size_t)((half * 12 + i) * 256 + t) * 4);
#pragma unroll
    for (int i = 0; i < 12; i++) {
      int f = (half * 12 + i) * 256 + t;
      int row = f / 192, cf = f - row * 192;
      f16x4 hh;
#pragma unroll
      for (int j = 0; j < 4; j++) hh[j] = (f16)v[i][j];
      *(f16x4*)&xt[row][cf * 4] = hh;
    }
  }
  __syncthreads();

  f32x4 acc[3][2];
#pragma unroll
  for (int i = 0; i < 3; i++) { acc[i][0] = (f32x4)0.0f; acc[i][1] = (f32x4)0.0f; }
  int j0 = w * 3;
  int mu0 = (j0 + 0) >> 2, ct0 = (j0 + 0) & 3;
  int mu1 = (j0 + 1) >> 2, ct1 = (j0 + 1) & 3;
  int mu2 = (j0 + 2) >> 2, ct2 = (j0 + 2) & 3;
  for (int ks = 0; ks < KSTEPS; ks += 2) {
    f16x8 b00 = wpk[((mu0 * KSTEPS + ks) * 4 + ct0) * 64 + lane];
    f16x8 b01 = wpk[((mu1 * KSTEPS + ks) * 4 + ct1) * 64 + lane];
    f16x8 b02 = wpk[((mu2 * KSTEPS + ks) * 4 + ct2) * 64 + lane];
    f16x8 b10 = wpk[((mu0 * KSTEPS + ks + 1) * 4 + ct0) * 64 + lane];
    f16x8 b11 = wpk[((mu1 * KSTEPS + ks + 1) * 4 + ct1) * 64 + lane];
    f16x8 b12 = wpk[((mu2 * KSTEPS + ks + 1) * 4 + ct2) * 64 + lane];
    f16x8 a00 = *(const f16x8*)&xt[l15][ks * 32 + quad * 8];
    f16x8 a01 = *(const f16x8*)&xt[16 + l15][ks * 32 + quad * 8];
    f16x8 a10 = *(const f16x8*)&xt[l15][ks * 32 + 32 + quad * 8];
    f16x8 a11 = *(const f16x8*)&xt[16 + l15][ks * 32 + 32 + quad * 8];
    acc[0][0] = __builtin_amdgcn_mfma_f32_16x16x32_f16(a00, b00, acc[0][0], 0, 0, 0);
    acc[0][1] = __builtin_amdgcn_mfma_f32_16x16x32_f16(a01, b00, acc[0][1], 0, 0, 0);
    acc[1][0] = __builtin_amdgcn_mfma_f32_16x16x32_f16(a00, b01, acc[1][0], 0, 0, 0);
    acc[1][1] = __builtin_amdgcn_mfma_f32_16x16x32_f16(a01, b01, acc[1][1], 0, 0, 0);
    acc[2][0] = __builtin_amdgcn_mfma_f32_16x16x32_f16(a00, b02, acc[2][0], 0, 0, 0);
    acc[2][1] = __builtin_amdgcn_mfma_f32_16x16x32_f16(a01, b02, acc[2][1], 0, 0, 0);
    acc[0][0] = __builtin_amdgcn_mfma_f32_16x16x32_f16(a10, b10, acc[0][0], 0, 0, 0);
    acc[0][1] = __builtin_amdgcn_mfma_f32_16x16x32_f16(a11, b10, acc[0][1], 0, 0, 0);
    acc[1][0] = __builtin_amdgcn_mfma_f32_16x16x32_f16(a10, b11, acc[1][0], 0, 0, 0);
    acc[1][1] = __builtin_amdgcn_mfma_f32_16x16x32_f16(a11, b11, acc[1][1], 0, 0, 0);
    acc[2][0] = __builtin_amdgcn_mfma_f32_16x16x32_f16(a10, b12, acc[2][0], 0, 0, 0);
    acc[2][1] = __builtin_amdgcn_mfma_f32_16x16x32_f16(a11, b12, acc[2][1], 0, 0, 0);
  }
  // C/D layout: col = l15, row = quad*4 + reg (token within row-group)
#pragma unroll
  for (int jj = 0; jj < 3; jj++) {
    int j = j0 + jj, mu = j >> 2, ct = j & 3;
#pragma unroll
    for (int rg = 0; rg < 2; rg++) {
      if (mu == 0) {
#pragma unroll
        for (int reg = 0; reg < 4; reg++)
          qb[(size_t)(r0 + rg * 16 + quad * 4 + reg) * HS + ct * 16 + l15] =
              (f16)acc[jj][rg][reg];
      } else if (mu == 1) {
#pragma unroll
        for (int reg = 0; reg < 4; reg++)
          klds[rg * 16 + quad * 4 + reg][ct * 16 + l15] = (f16)acc[jj][rg][reg];
      } else {
#pragma unroll
        for (int reg = 0; reg < 4; reg++)
          vtl[ct * 16 + l15][rg * 16 + quad * 4 + reg] = (f16)acc[jj][rg][reg];
      }
    }
  }
  __syncthreads();
  // repack into kvt tile (same layout as r7). Block covers slices
  // kt in {2h, 2h+1} of tile tt (K) and keys [h*32, h*32+32) (V, ks=h).
  f16* tbase = kvt + (size_t)(b * 64 + tt) * 8192;
  {
    int pidx = t >> 6, lam = t & 63;
    int ks = pidx >> 1, sl = pidx & 1;
    f16x8 hk = *(const f16x8*)&klds[sl * 16 + (lam & 15)][ks * 32 + (lam >> 4) * 8];
    *(f16x8*)(tbase + (ks * 4 + 2 * h + sl) * 512 + lam * 8) = hk;
    int dt = pidx;
    f16x8 hv = *(const f16x8*)&vtl[dt * 16 + (lam & 15)][(lam >> 4) * 8];
    *(f16x8*)(tbase + (8 + h * 4 + dt) * 512 + lam * 8) = hv;
  }
}

// ---------------------------------------------------------------------------
// Attention: double-buffered LDS staging of 16 KB K/V tiles via
// global_load_lds (width 16); fragment reads are conflict-free ds_read_b128.
// ---------------------------------------------------------------------------
#define STAGE(BUF, TILE) do { \
  const f16* _s = kv_b + (size_t)(TILE) * 8192 + (size_t)threadIdx.x * 8; \
  _Pragma("unroll") \
  for (int _k = 0; _k < 4; _k++) \
    __builtin_amdgcn_global_load_lds( \
        (const __attribute__((address_space(1))) unsigned int*)(_s + _k * 2048), \
        (__attribute__((address_space(3))) unsigned int*)&(BUF)[_k * 2048 + w * 512], \
        16, 0, 0); \
} while (0)

#define ATTN_STEP(CUR, KBK) do { \
  const int _key0 = (KBK) * 64; \
  f16x8 _kf[2][4]; \
  _Pragma("unroll") \
  for (int _ks = 0; _ks < 2; _ks++) \
    _Pragma("unroll") \
    for (int _kt = 0; _kt < 4; _kt++) \
      _kf[_ks][_kt] = *(const f16x8*)&(CUR)[(_ks * 4 + _kt) * 512 + lane * 8]; \
  f32x4 _sc[4]; \
  _Pragma("unroll") for (int _kt = 0; _kt < 4; _kt++) _sc[_kt] = (f32x4)0.0f; \
  _Pragma("unroll") \
  for (int _ks = 0; _ks < 2; _ks++) \
    _Pragma("unroll") \
    for (int _kt = 0; _kt < 4; _kt++) \
      _sc[_kt] = __builtin_amdgcn_mfma_f32_16x16x32_f16(_kf[_ks][_kt], qa[_ks], _sc[_kt], 0, 0, 0); \
  f16x8 _vf[2][4]; \
  _Pragma("unroll") \
  for (int _ks = 0; _ks < 2; _ks++) \
    _Pragma("unroll") \
    for (int _dt = 0; _dt < 4; _dt++) \
      _vf[_ks][_dt] = *(const f16x8*)&(CUR)[(8 + _ks * 4 + _dt) * 512 + lane * 8]; \
  if ((KBK) == qt) { \
    _Pragma("unroll") \
    for (int _kt = 0; _kt < 4; _kt++) { \
      int _keyb = _key0 + _kt * 16 + quad * 4; \
      _Pragma("unroll") \
      for (int _r = 0; _r < 4; _r++) \
        if (_keyb + _r > qrow) _sc[_kt][_r] = -INFINITY; \
    } \
  } \
  float _mx; \
  { float _a0 = fmaxf(fmaxf(_sc[0][0], _sc[0][1]), fmaxf(_sc[0][2], _sc[0][3])); \
    float _a1 = fmaxf(fmaxf(_sc[1][0], _sc[1][1]), fmaxf(_sc[1][2], _sc[1][3])); \
    float _a2 = fmaxf(fmaxf(_sc[2][0], _sc[2][1]), fmaxf(_sc[2][2], _sc[2][3])); \
    float _a3 = fmaxf(fmaxf(_sc[3][0], _sc[3][1]), fmaxf(_sc[3][2], _sc[3][3])); \
    _mx = fmaxf(fmaxf(_a0, _a1), fmaxf(_a2, _a3)); } \
  _mx = fmaxf(_mx, __shfl_xor(_mx, 16, 64)); \
  _mx = fmaxf(_mx, __shfl_xor(_mx, 32, 64)); \
  float _mn = fmaxf(m, _mx); \
  float _alpha = __expf(m - _mn); \
  m = _mn; \
  float _sum = 0.0f; \
  _Pragma("unroll") \
  for (int _kt = 0; _kt < 4; _kt++) { \
    float _s0 = __expf(_sc[_kt][0] - _mn), _s1 = __expf(_sc[_kt][1] - _mn); \
    float _s2 = __expf(_sc[_kt][2] - _mn), _s3 = __expf(_sc[_kt][3] - _mn); \
    f16x4 _h; _h[0] = (f16)_s0; _h[1] = (f16)_s1; _h[2] = (f16)_s2; _h[3] = (f16)_s3; \
    *(f16x4*)&pbuf[w][l15][_kt * 16 + quad * 4] = _h; \
    _sum += (_s0 + _s1) + (_s2 + _s3); } \
  _sum += __shfl_xor(_sum, 16, 64); \
  _sum += __shfl_xor(_sum, 32, 64); \
  l = l * _alpha + _sum; \
  _Pragma("unroll") for (int _dt = 0; _dt < 4; _dt++) o[_dt] *= _alpha; \
  _Pragma("unroll") \
  for (int _ks = 0; _ks < 2; _ks++) { \
    f16x8 _pf = *(const f16x8*)&pbuf[w][l15][_ks * 32 + quad * 8]; \
    _Pragma("unroll") \
    for (int _dt = 0; _dt < 4; _dt++) \
      o[_dt] = __builtin_amdgcn_mfma_f32_16x16x32_f16(_vf[_ks][_dt], _pf, o[_dt], 0, 0, 0); } \
} while (0)

__global__ __launch_bounds__(256) void attn_part(const f16* __restrict__ qb,
                                                 const f16* __restrict__ kvt,
                                                 f16* __restrict__ opart,
                                                 float* __restrict__ ml) {
  __shared__ __align__(16) f16 kvbuf[2][8192];   // 32 KB double buffer
  __shared__ __align__(16) f16 pbuf[4][16][72];
  int w = threadIdx.x >> 6, lane = threadIdx.x & 63;
  int l15 = lane & 15, quad = lane >> 4;
  int id = blockIdx.x;                           // 1152 blocks
  int b = (id & 7) >> 1;                         // batch -> XCD pair
  int p = 287 - (((id >> 3) << 1) | (id & 1));   // longest segments first
  int g = 0;
  while (p >= 4 * (g + 1) * (g + 2)) g++;
  int rem = p - 4 * g * (g + 1);
  int j = rem / (g + 1);
  int s = rem - j * (g + 1);
  int qt = 8 * g + j;
  int kb_beg = s * 8;
  int kb_end = (s * 8 + 8 < qt + 1) ? (s * 8 + 8) : (qt + 1);

  int qr0 = qt * 64 + w * 16;
  int gq = b * SEQ + qr0;
  int qrow = qr0 + l15;

  const f16* kv_b = kvt + (size_t)b * 64 * 8192;
  STAGE(kvbuf[0], kb_beg);

  f16x8 qa[2];
  {
    const f16* qrp = qb + (size_t)(gq + l15) * HS + quad * 8;
    qa[0] = *(const f16x8*)(qrp);
    qa[1] = *(const f16x8*)(qrp + 32);
  }
  f32x4 o[4];
#pragma unroll
  for (int i = 0; i < 4; i++) o[i] = (f32x4)0.0f;
  float m = -INFINITY, l = 0.0f;

  int cur = 0;
  for (int i = kb_beg; i < kb_end; i++) {
    __syncthreads();                             // staging of cur complete
    if (i + 1 < kb_end) STAGE(kvbuf[cur ^ 1], i + 1);
    ATTN_STEP(kvbuf[cur], i);
    cur ^= 1;
  }

  int slot = (b * 64 + qt) * 8 + s;
  f16* op = opart + (size_t)slot * 4096;
#pragma unroll
  for (int dt = 0; dt < 4; dt++) {
    f16x4 h;
#pragma unroll
    for (int reg = 0; reg < 4; reg++) h[reg] = (f16)o[dt][reg];
    *(f16x4*)&op[(w * 16 + l15) * 64 + dt * 16 + quad * 4] = h;
  }
  if (quad == 0) {
    ml[slot * 128 + w * 16 + l15] = m;
    ml[slot * 128 + 64 + w * 16 + l15] = l;
  }
}

// ---------------------------------------------------------------------------
// Combine: 512 blocks, XCD-swizzled to the batch's XCD pair.
// ---------------------------------------------------------------------------
__global__ __launch_bounds__(256) void attn_combine(const f16* __restrict__ opart,
                                                    const float* __restrict__ ml,
                                                    float* __restrict__ out) {
  int id = blockIdx.x;
  int b = (id & 7) >> 1;
  int rest = ((id >> 3) << 1) | (id & 1);        // [0,128)
  int qt = rest >> 1, h = rest & 1;
  int nseg = (qt >> 3) + 1;
  int tid = threadIdx.x;
  int r = h * 32 + (tid >> 3), d0 = (tid & 7) * 8;
  int base_slot = (b * 64 + qt) * 8;

  float mv[8], lv[8];
#pragma unroll
  for (int s = 0; s < 8; s++) {
    if (s < nseg) {
      mv[s] = ml[(base_slot + s) * 128 + r];
      lv[s] = ml[(base_slot + s) * 128 + 64 + r];
    } else { mv[s] = -INFINITY; lv[s] = 0.0f; }
  }
  float M = -INFINITY;
#pragma unroll
  for (int s = 0; s < 8; s++) M = fmaxf(M, mv[s]);
  float e[8], L = 0.0f;
#pragma unroll
  for (int s = 0; s < 8; s++) { e[s] = __expf(mv[s] - M); L += lv[s] * e[s]; }
  float acc[8];
#pragma unroll
  for (int i = 0; i < 8; i++) acc[i] = 0.0f;
  const f16* obase = opart + (size_t)base_slot * 4096 + r * 64 + d0;
  int s = 0;
  for (; s + 4 <= nseg; s += 4) {
    f16x8 a0 = *(const f16x8*)(obase + (size_t)(s + 0) * 4096);
    f16x8 a1 = *(const f16x8*)(obase + (size_t)(s + 1) * 4096);
    f16x8 a2 = *(const f16x8*)(obase + (size_t)(s + 2) * 4096);
    f16x8 a3 = *(const f16x8*)(obase + (size_t)(s + 3) * 4096);
#pragma unroll
    for (int i = 0; i < 8; i++)
      acc[i] += e[s] * (float)a0[i] + e[s + 1] * (float)a1[i] +
                e[s + 2] * (float)a2[i] + e[s + 3] * (float)a3[i];
  }
  for (; s < nseg; s++) {
    f16x8 a = *(const f16x8*)(obase + (size_t)s * 4096);
#pragma unroll
    for (int i = 0; i < 8; i++) acc[i] += e[s] * (float)a[i];
  }
  float inv = 1.0f / L;
  float* po = out + ((size_t)(b * SEQ + qt * 64 + r)) * HS + d0;
#pragma unroll
  for (int i = 0; i < 8; i++) po[i] = acc[i] * inv;
}

// ---------------------------------------------------------------------------
// Fallback monolithic attention (ws too small for opart/ml).
// ---------------------------------------------------------------------------
__global__ __launch_bounds__(256) void attn_mono(const f16* __restrict__ qb,
                                                 const f16* __restrict__ kvt,
                                                 float* __restrict__ out) {
  __shared__ __align__(16) f16 kvbuf[2][8192];
  __shared__ __align__(16) f16 pbuf[4][16][72];
  int w = threadIdx.x >> 6, lane = threadIdx.x & 63;
  int l15 = lane & 15, quad = lane >> 4;
  int qt = blockIdx.x, b = blockIdx.y;
  int qr0 = qt * 64 + w * 16;
  int gq = b * SEQ + qr0;
  int qrow = qr0 + l15;
  const f16* kv_b = kvt + (size_t)b * 64 * 8192;
  STAGE(kvbuf[0], 0);
  f16x8 qa[2];
  {
    const f16* qrp = qb + (size_t)(gq + l15) * HS + quad * 8;
    qa[0] = *(const f16x8*)(qrp);
    qa[1] = *(const f16x8*)(qrp + 32);
  }
  f32x4 o[4];
#pragma unroll
  for (int i = 0; i < 4; i++) o[i] = (f32x4)0.0f;
  float m = -INFINITY, l = 0.0f;
  int cur = 0;
  for (int i = 0; i <= qt; i++) {
    __syncthreads();
    if (i + 1 <= qt) STAGE(kvbuf[cur ^ 1], i + 1);
    ATTN_STEP(kvbuf[cur], i);
    cur ^= 1;
  }
  float inv = 1.0f / l;
#pragma unroll
  for (int dt = 0; dt < 4; dt++)
#pragma unroll
    for (int reg = 0; reg < 4; reg++)
      out[(size_t)(b * SEQ + qr0 + l15) * HS + dt * 16 + quad * 4 + reg] = o[dt][reg] * inv;
}

extern "C" void kernel_launch(void* const* d_in, const int* in_sizes, int n_in,
                              void* d_out, int out_size, void* d_ws, size_t ws_size,
                              hipStream_t stream) {
  const float* x  = (const float*)d_in[0];
  const float* Wk = (const float*)d_in[1];
  const float* Wq = (const float*)d_in[2];
  const float* Wv = (const float*)d_in[3];
  float* out = (float*)d_out;

  f16* wpk = (f16*)d_ws;
  f16* qb  = (f16*)((char*)d_ws + OFF_Q);
  f16* kvt = (f16*)((char*)d_ws + OFF_KV);
  f16* opart = (f16*)((char*)d_ws + OFF_OP);
  float* ml = (float*)((char*)d_ws + OFF_ML);

  pack_w<<<dim3(72), dim3(256), 0, stream>>>(Wk, Wq, Wv, wpk);
  proj<<<dim3(NTOK / 32), dim3(256), 0, stream>>>(x, (const f16x8*)wpk, qb, kvt);
  if (ws_size >= (size_t)WS_NEED) {
    attn_part<<<dim3(288 * NB), dim3(256), 0, stream>>>(qb, kvt, opart, ml);
    attn_combine<<<dim3(512), dim3(256), 0, stream>>>(opart, ml, out);
  } else {
    attn_mono<<<dim3(SEQ / 64, NB), dim3(256), 0, stream>>>(qb, kvt, out);
  }
}